// Round 8
// baseline (480.873 us; speedup 1.0000x reference)
//
#include <hip/hip_runtime.h>

#define S 1024
#define D 64
#define R 16            // rows per block
#define BH 64           // B*H
#define WST 264         // w_lds stride in bf16 elems (256 + 8 pad -> conflict-free)

typedef float  v4f  __attribute__((ext_vector_type(4)));
typedef float  f32x4 __attribute__((ext_vector_type(4)));
typedef short  short4v __attribute__((ext_vector_type(4)));
typedef short  short8v __attribute__((ext_vector_type(8)));

__device__ __forceinline__ short f2bf(float f) {
    unsigned u = __builtin_bit_cast(unsigned, f);
    u += 0x7fff + ((u >> 16) & 1);          // RNE
    return (short)(u >> 16);
}

// ---------------- pre-pass: kT[t][d] and vT[d][t] in bf16 ----------------
__global__ __launch_bounds__(256)
void transpose_bf16_kernel(const float* __restrict__ k,   // [BH][D][S]
                           const float* __restrict__ v,   // [BH][S][D]
                           short* __restrict__ kT,        // [BH][S][D] bf16
                           short* __restrict__ vT)        // [BH][D][S] bf16
{
    __shared__ float lds[64][65];
    const int t0 = blockIdx.x * 64;
    const int bh = blockIdx.y;
    const int z  = blockIdx.z;
    const int ty = (int)threadIdx.x >> 4;        // 0..15
    const int c4 = ((int)threadIdx.x & 15) * 4;  // 0,4..60

    if (z == 0) {
        const float* src = k + (size_t)bh * D * S;
#pragma unroll
        for (int it = 0; it < 4; ++it) {
            int d = it * 16 + ty;
            float4 ld = *(const float4*)(src + (size_t)d * S + t0 + c4);
            *(float4*)&lds[d][c4] = ld;                      // lds[d][tloc]
        }
        __syncthreads();
        short* dst = kT + (size_t)bh * S * D;
#pragma unroll
        for (int it = 0; it < 4; ++it) {
            int tl = it * 16 + ty;
            short4v st = { f2bf(lds[c4 + 0][tl]), f2bf(lds[c4 + 1][tl]),
                           f2bf(lds[c4 + 2][tl]), f2bf(lds[c4 + 3][tl]) };
            *(short4v*)(dst + (size_t)(t0 + tl) * D + c4) = st;   // kT[t][d]
        }
    } else {
        const float* src = v + (size_t)bh * S * D;
#pragma unroll
        for (int it = 0; it < 4; ++it) {
            int tl = it * 16 + ty;
            float4 ld = *(const float4*)(src + (size_t)(t0 + tl) * D + c4);
            *(float4*)&lds[tl][c4] = ld;                     // lds[tloc][d]
        }
        __syncthreads();
        short* dst = vT + (size_t)bh * D * S;
#pragma unroll
        for (int it = 0; it < 4; ++it) {
            int d = it * 16 + ty;
            short4v st = { f2bf(lds[c4 + 0][d]), f2bf(lds[c4 + 1][d]),
                           f2bf(lds[c4 + 2][d]), f2bf(lds[c4 + 3][d]) };
            *(short4v*)(dst + (size_t)d * S + t0 + c4) = st;      // vT[d][t]
        }
    }
}

// ---------------- main fused kernel (MFMA) ----------------
__global__ __launch_bounds__(256, 4)
void attn_mfma_kernel(const float* __restrict__ q,
                      const short* __restrict__ kT,     // [BH][S][D] bf16
                      const short* __restrict__ vT,     // [BH][D][S] bf16
                      const float* __restrict__ prev,   // [BH][S][S]
                      const float* __restrict__ mask,   // [S][S]
                      const float* __restrict__ scale_p,
                      float* __restrict__ out,          // [BH][S][D]
                      float* __restrict__ weights,      // [BH][S][S]
                      float* __restrict__ scores)       // [BH][S][S]
{
    __shared__ float q_lds[R][68];                 // 4.3 KB
    __shared__ short w_lds[4][R][WST];             // 33.8 KB (reused for fp32 partials)
    __shared__ float red_sum[4][R];

    // XCD-bijective swizzle (R7-proven)
    const int bid  = (int)blockIdx.x;              // 0..4095
    const int wg   = (bid & 7) * 512 + (bid >> 3);
    const int tile = wg & 63;
    const int bh   = wg >> 6;

    const int tid  = (int)threadIdx.x;
    const int lane = tid & 63;
    const int wid  = tid >> 6;
    const int g    = lane >> 4;        // k-group
    const int c    = lane & 15;        // n-index / col
    const int r0   = tile * R;

    const float scale = *scale_p;

    const float* qb  = q    + (size_t)bh * S * D + (size_t)r0 * D;
    const short* kTb = kT   + (size_t)bh * S * D;
    const short* vTw = vT   + (size_t)bh * D * S + wid * 256;  // (d, tloc): d*S + tloc
    float* oout = out + (size_t)bh * S * D + (size_t)r0 * D;

    // row/col bases for the MFMA lane mapping: rows r0+4g+reg, col t = wid*256 + i*16 + c
    const size_t rowbase = (size_t)(r0 + 4 * g) * S + wid * 256 + c;
    const float* pb2 = prev + (size_t)bh * S * S + rowbase;
    const float* mb2 = mask + rowbase;
    float* sout2 = scores  + (size_t)bh * S * S + rowbase;
    float* wout2 = weights + (size_t)bh * S * S + rowbase;

    // ---- load Q tile (16x64) to LDS ----
    {
        float4 qv = *(const float4*)(qb + (size_t)tid * 4);
        *(float4*)&q_lds[tid >> 4][(tid & 15) * 4] = qv;
    }
    __syncthreads();

    // ---- build A-fragments of Q (bf16): lane row = c; elems 0-3: k=4g+j, 4-7: k=16+4g+j ----
    short8v aq[2];
#pragma unroll
    for (int h = 0; h < 2; ++h) {
        float4 lo = *(const float4*)&q_lds[c][32 * h + 4 * g];
        float4 hi = *(const float4*)&q_lds[c][32 * h + 16 + 4 * g];
        short8v a = { f2bf(lo.x), f2bf(lo.y), f2bf(lo.z), f2bf(lo.w),
                      f2bf(hi.x), f2bf(hi.y), f2bf(hi.z), f2bf(hi.w) };
        aq[h] = a;
    }

    // ---- QK^T: 16 t-tiles per wave, 2 MFMAs each ----
    f32x4 acc[16];
#pragma unroll
    for (int i = 0; i < 16; ++i) {
        const short* kp = kTb + (size_t)(wid * 256 + i * 16 + c) * D;
        short4v b0lo = *(const short4v*)(kp + 4 * g);
        short4v b0hi = *(const short4v*)(kp + 16 + 4 * g);
        short4v b1lo = *(const short4v*)(kp + 32 + 4 * g);
        short4v b1hi = *(const short4v*)(kp + 48 + 4 * g);
        short8v bk0 = __builtin_shufflevector(b0lo, b0hi, 0, 1, 2, 3, 4, 5, 6, 7);
        short8v bk1 = __builtin_shufflevector(b1lo, b1hi, 0, 1, 2, 3, 4, 5, 6, 7);
        f32x4 cc = {0.f, 0.f, 0.f, 0.f};
        cc = __builtin_amdgcn_mfma_f32_16x16x32_bf16(aq[0], bk0, cc, 0, 0, 0);
        cc = __builtin_amdgcn_mfma_f32_16x16x32_bf16(aq[1], bk1, cc, 0, 0, 0);
        acc[i] = cc;
    }

    // ---- epilogue: scores = qk*scale + prev + mask; exp; row sums ----
    float rowsum[4] = {0.f, 0.f, 0.f, 0.f};
#pragma unroll
    for (int i = 0; i < 16; ++i) {
#pragma unroll
        for (int reg = 0; reg < 4; ++reg) {
            float pv = __builtin_nontemporal_load(pb2 + (size_t)reg * S + i * 16);
            float mv = mb2[(size_t)reg * S + i * 16];
            float sc = fmaf(acc[i][reg], scale, pv + mv);
            __builtin_nontemporal_store(sc, sout2 + (size_t)reg * S + i * 16);
            float e = __expf(sc);
            acc[i][reg] = e;
            rowsum[reg] += e;
        }
    }
    // reduce over the 16-lane group (t direction within wave)
#pragma unroll
    for (int reg = 0; reg < 4; ++reg) {
#pragma unroll
        for (int off = 1; off < 16; off <<= 1)
            rowsum[reg] += __shfl_xor(rowsum[reg], off);
    }
    if (c == 0) {
#pragma unroll
        for (int reg = 0; reg < 4; ++reg) red_sum[wid][4 * g + reg] = rowsum[reg];
    }
    __syncthreads();

    float inv[4];
#pragma unroll
    for (int reg = 0; reg < 4; ++reg) {
        int r = 4 * g + reg;
        inv[reg] = 1.0f / ((red_sum[0][r] + red_sum[1][r]) + (red_sum[2][r] + red_sum[3][r]));
    }

    // ---- weights: fp32 to global (nt), bf16 to wave-private LDS ----
    asm volatile("" ::: "memory");
#pragma unroll
    for (int i = 0; i < 16; ++i) {
#pragma unroll
        for (int reg = 0; reg < 4; ++reg) {
            float wv = acc[i][reg] * inv[reg];
            __builtin_nontemporal_store(wv, wout2 + (size_t)reg * S + i * 16);
            w_lds[wid][4 * g + reg][i * 16 + c] = f2bf(wv);
        }
    }
    asm volatile("s_waitcnt lgkmcnt(0)" ::: "memory");

    // ---- PV: O[16r][64d] per wave over its 256-t slice; A=W(LDS), B=vT(global) ----
    f32x4 pst[4];
#pragma unroll
    for (int dt = 0; dt < 4; ++dt) {
        f32x4 po = {0.f, 0.f, 0.f, 0.f};
#pragma unroll
        for (int ks = 0; ks < 8; ++ks) {
            const int tc = ks * 32;
            short4v alo = *(const short4v*)&w_lds[wid][c][tc + 4 * g];
            short4v ahi = *(const short4v*)&w_lds[wid][c][tc + 16 + 4 * g];
            short8v aw = __builtin_shufflevector(alo, ahi, 0, 1, 2, 3, 4, 5, 6, 7);
            const short* vp = vTw + (size_t)(dt * 16 + c) * S + tc;
            short4v blo = *(const short4v*)(vp + 4 * g);
            short4v bhi = *(const short4v*)(vp + 16 + 4 * g);
            short8v bv = __builtin_shufflevector(blo, bhi, 0, 1, 2, 3, 4, 5, 6, 7);
            po = __builtin_amdgcn_mfma_f32_16x16x32_bf16(aw, bv, po, 0, 0, 0);
        }
        pst[dt] = po;
    }

    // ---- stash partials into own wave's (now dead) W region as fp32 ----
    asm volatile("" ::: "memory");
    {
        float* pw = (float*)&w_lds[wid][0][0];
#pragma unroll
        for (int dt = 0; dt < 4; ++dt) {
#pragma unroll
            for (int reg = 0; reg < 4; ++reg)
                pw[(4 * g + reg) * 64 + dt * 16 + c] = pst[dt][reg];
        }
    }
    __syncthreads();

    // ---- cross-wave sum + out store ----
    {
        const int row = tid >> 4;       // 0..15
        const int dc  = (tid & 15) * 4; // 0..60
        v4f o = {0.f, 0.f, 0.f, 0.f};
#pragma unroll
        for (int w = 0; w < 4; ++w) {
            const float* pw = (const float*)&w_lds[w][0][0];
            float4 a = *(const float4*)&pw[row * 64 + dc];
            o[0] += a.x; o[1] += a.y; o[2] += a.z; o[3] += a.w;
        }
        __builtin_nontemporal_store(o, (v4f*)(oout + (size_t)row * D + dc));
    }
}

extern "C" void kernel_launch(void* const* d_in, const int* in_sizes, int n_in,
                              void* d_out, int out_size, void* d_ws, size_t ws_size,
                              hipStream_t stream) {
    (void)in_sizes; (void)n_in; (void)out_size; (void)ws_size;
    const float* q     = (const float*)d_in[0];
    const float* k     = (const float*)d_in[1];
    const float* v     = (const float*)d_in[2];
    const float* prev  = (const float*)d_in[3];
    const float* mask  = (const float*)d_in[4];
    const float* scale = (const float*)d_in[5];

    float* out     = (float*)d_out;
    float* weights = out + (size_t)4 * 16 * 1024 * 64;
    float* scores  = weights + (size_t)4 * 16 * 1024 * 1024;

    short* kT = (short*)d_ws;                              // [BH][S][D] bf16, 8 MB
    short* vT = kT + (size_t)BH * S * D;                   // [BH][D][S] bf16, 8 MB

    transpose_bf16_kernel<<<dim3(16, BH, 2), 256, 0, stream>>>(k, v, kT, vT);
    attn_mfma_kernel<<<dim3(4096), 256, 0, stream>>>(q, kT, vT, prev, mask, scale,
                                                     out, weights, scores);
}

// Round 9
// 444.489 us; speedup vs baseline: 1.0819x; 1.0819x over previous
//
#include <hip/hip_runtime.h>

#define S 1024
#define D 64
#define R 16            // rows per block
#define BH 64           // B*H

typedef float  v4f     __attribute__((ext_vector_type(4)));
typedef float  f32x4   __attribute__((ext_vector_type(4)));
typedef short  short4v __attribute__((ext_vector_type(4)));
typedef short  short8v __attribute__((ext_vector_type(8)));

__device__ __forceinline__ short f2bf(float f) {
    unsigned u = __builtin_bit_cast(unsigned, f);
    u += 0x7fff + ((u >> 16) & 1);          // RNE
    return (short)(u >> 16);
}

// ---------------- pre-pass: kT[t][d] and vT[d][t] in bf16 (unchanged) ----------------
__global__ __launch_bounds__(256)
void transpose_bf16_kernel(const float* __restrict__ k,   // [BH][D][S]
                           const float* __restrict__ v,   // [BH][S][D]
                           short* __restrict__ kT,        // [BH][S][D] bf16
                           short* __restrict__ vT)        // [BH][D][S] bf16
{
    __shared__ float lds[64][65];
    const int t0 = blockIdx.x * 64;
    const int bh = blockIdx.y;
    const int z  = blockIdx.z;
    const int ty = (int)threadIdx.x >> 4;
    const int c4 = ((int)threadIdx.x & 15) * 4;

    if (z == 0) {
        const float* src = k + (size_t)bh * D * S;
#pragma unroll
        for (int it = 0; it < 4; ++it) {
            int d = it * 16 + ty;
            float4 ld = *(const float4*)(src + (size_t)d * S + t0 + c4);
            *(float4*)&lds[d][c4] = ld;
        }
        __syncthreads();
        short* dst = kT + (size_t)bh * S * D;
#pragma unroll
        for (int it = 0; it < 4; ++it) {
            int tl = it * 16 + ty;
            short4v st = { f2bf(lds[c4 + 0][tl]), f2bf(lds[c4 + 1][tl]),
                           f2bf(lds[c4 + 2][tl]), f2bf(lds[c4 + 3][tl]) };
            *(short4v*)(dst + (size_t)(t0 + tl) * D + c4) = st;
        }
    } else {
        const float* src = v + (size_t)bh * S * D;
#pragma unroll
        for (int it = 0; it < 4; ++it) {
            int tl = it * 16 + ty;
            float4 ld = *(const float4*)(src + (size_t)(t0 + tl) * D + c4);
            *(float4*)&lds[tl][c4] = ld;
        }
        __syncthreads();
        short* dst = vT + (size_t)bh * D * S;
#pragma unroll
        for (int it = 0; it < 4; ++it) {
            int d = it * 16 + ty;
            short4v st = { f2bf(lds[c4 + 0][d]), f2bf(lds[c4 + 1][d]),
                           f2bf(lds[c4 + 2][d]), f2bf(lds[c4 + 3][d]) };
            *(short4v*)(dst + (size_t)d * S + t0 + c4) = st;
        }
    }
}

// ---------------- main fused kernel: swapped-operand MFMA ----------------
__global__ __launch_bounds__(256, 4)
void attn_mfma_kernel(const float* __restrict__ q,
                      const short* __restrict__ kT,     // [BH][S][D] bf16
                      const short* __restrict__ vT,     // [BH][D][S] bf16
                      const float* __restrict__ prev,   // [BH][S][S]
                      const float* __restrict__ mask,   // [S][S]
                      const float* __restrict__ scale_p,
                      float* __restrict__ out,          // [BH][S][D]
                      float* __restrict__ weights,      // [BH][S][S]
                      float* __restrict__ scores)       // [BH][S][S]
{
    __shared__ float s_out[4][R][68];   // 17.4 KB cross-wave O-partials
    __shared__ float red_sum[4][R];

    // XCD-bijective swizzle (R7-proven)
    const int bid  = (int)blockIdx.x;
    const int wg   = (bid & 7) * 512 + (bid >> 3);
    const int tile = wg & 63;
    const int bh   = wg >> 6;

    const int tid  = (int)threadIdx.x;
    const int lane = tid & 63;
    const int wid  = tid >> 6;
    const int g    = lane >> 4;        // k-group / t-subrow group
    const int c    = lane & 15;        // q-row within tile
    const int r0   = tile * R;

    const float scale = *scale_p;

    // ---- Q B-fragment direct from global: B[col=q-row=c][k=d] ----
    const float* qrow = q + ((size_t)bh * S + r0 + c) * D;
    short8v bq[2];
#pragma unroll
    for (int h = 0; h < 2; ++h) {
        float4 lo = *(const float4*)(qrow + 32 * h + 4 * g);
        float4 hi = *(const float4*)(qrow + 32 * h + 16 + 4 * g);
        short8v b = { f2bf(lo.x), f2bf(lo.y), f2bf(lo.z), f2bf(lo.w),
                      f2bf(hi.x), f2bf(hi.y), f2bf(hi.z), f2bf(hi.w) };
        bq[h] = b;
    }

    // ---- QK^T swapped: acc[i] = S^T tile -> lane owns S[r0+c][wid*256+16i+4g+reg] ----
    const short* kTw = kT + (size_t)bh * S * D + (size_t)(wid * 256) * D;
    f32x4 acc[16];
#pragma unroll
    for (int i = 0; i < 16; ++i) {
        const short* kp = kTw + (size_t)(i * 16 + c) * D;   // A row = t
        short4v a0lo = *(const short4v*)(kp + 4 * g);
        short4v a0hi = *(const short4v*)(kp + 16 + 4 * g);
        short4v a1lo = *(const short4v*)(kp + 32 + 4 * g);
        short4v a1hi = *(const short4v*)(kp + 48 + 4 * g);
        short8v ak0 = __builtin_shufflevector(a0lo, a0hi, 0, 1, 2, 3, 4, 5, 6, 7);
        short8v ak1 = __builtin_shufflevector(a1lo, a1hi, 0, 1, 2, 3, 4, 5, 6, 7);
        f32x4 cc = {0.f, 0.f, 0.f, 0.f};
        cc = __builtin_amdgcn_mfma_f32_16x16x32_bf16(ak0, bq[0], cc, 0, 0, 0);
        cc = __builtin_amdgcn_mfma_f32_16x16x32_bf16(ak1, bq[1], cc, 0, 0, 0);
        acc[i] = cc;
    }

    // ---- epilogue: fully vectorized float4 on row r0+c ----
    const size_t rowoff = ((size_t)(r0 + c)) * S + wid * 256 + 4 * g;
    const float* pb2 = prev + (size_t)bh * S * S + rowoff;
    const float* mb2 = mask + rowoff;
    float* sout2 = scores  + (size_t)bh * S * S + rowoff;
    float* wout2 = weights + (size_t)bh * S * S + rowoff;

    float lsum = 0.f;
#pragma unroll
    for (int i = 0; i < 16; ++i) {
        v4f p4 = __builtin_nontemporal_load((const v4f*)(pb2 + i * 16));
        v4f m4 = *(const v4f*)(mb2 + i * 16);
        v4f sc;
#pragma unroll
        for (int r = 0; r < 4; ++r)
            sc[r] = fmaf(acc[i][r], scale, p4[r] + m4[r]);
        __builtin_nontemporal_store(sc, (v4f*)(sout2 + i * 16));
#pragma unroll
        for (int r = 0; r < 4; ++r) {
            float e = __expf(sc[r]);
            acc[i][r] = e;
            lsum += e;
        }
    }
    // row r0+c sum: combine the 4 g-groups, then cross-wave
    lsum += __shfl_xor(lsum, 16);
    lsum += __shfl_xor(lsum, 32);
    if (g == 0) red_sum[wid][c] = lsum;
    __syncthreads();
    const float inv = 1.0f / ((red_sum[0][c] + red_sum[1][c]) +
                              (red_sum[2][c] + red_sum[3][c]));

    // ---- normalize + weights (nt float4); keep W in acc ----
#pragma unroll
    for (int i = 0; i < 16; ++i) {
        v4f w4;
#pragma unroll
        for (int r = 0; r < 4; ++r) w4[r] = acc[i][r] * inv;
        __builtin_nontemporal_store(w4, (v4f*)(wout2 + i * 16));
        acc[i] = w4;
    }

    // ---- PV A-fragments straight from registers (no LDS relay) ----
    short8v paw[8];
#pragma unroll
    for (int ks = 0; ks < 8; ++ks) {
        short8v a = { f2bf(acc[2 * ks][0]),     f2bf(acc[2 * ks][1]),
                      f2bf(acc[2 * ks][2]),     f2bf(acc[2 * ks][3]),
                      f2bf(acc[2 * ks + 1][0]), f2bf(acc[2 * ks + 1][1]),
                      f2bf(acc[2 * ks + 1][2]), f2bf(acc[2 * ks + 1][3]) };
        paw[ks] = a;
    }

    // ---- PV: O_part[q-row 4g+reg][d 16dt+c] over this wave's 256-t slice ----
    const short* vTw = vT + (size_t)bh * D * S + wid * 256;
    f32x4 pst[4];
#pragma unroll
    for (int dt = 0; dt < 4; ++dt) {
        f32x4 po = {0.f, 0.f, 0.f, 0.f};
#pragma unroll
        for (int ks = 0; ks < 8; ++ks) {
            const short* vp = vTw + (size_t)(dt * 16 + c) * S + ks * 32 + 4 * g;
            short4v blo = *(const short4v*)(vp);
            short4v bhi = *(const short4v*)(vp + 16);
            short8v bv = __builtin_shufflevector(blo, bhi, 0, 1, 2, 3, 4, 5, 6, 7);
            po = __builtin_amdgcn_mfma_f32_16x16x32_bf16(paw[ks], bv, po, 0, 0, 0);
        }
        pst[dt] = po;
    }

    // ---- stash partials, cross-wave sum, vectorized out store ----
#pragma unroll
    for (int dt = 0; dt < 4; ++dt) {
#pragma unroll
        for (int reg = 0; reg < 4; ++reg)
            s_out[wid][4 * g + reg][dt * 16 + c] = pst[dt][reg];
    }
    __syncthreads();
    {
        const int row = tid >> 4;       // 0..15
        const int dc  = (tid & 15) * 4; // 0..60
        float4 a0 = *(const float4*)&s_out[0][row][dc];
        float4 a1 = *(const float4*)&s_out[1][row][dc];
        float4 a2 = *(const float4*)&s_out[2][row][dc];
        float4 a3 = *(const float4*)&s_out[3][row][dc];
        v4f o;
        o[0] = (a0.x + a1.x) + (a2.x + a3.x);
        o[1] = (a0.y + a1.y) + (a2.y + a3.y);
        o[2] = (a0.z + a1.z) + (a2.z + a3.z);
        o[3] = (a0.w + a1.w) + (a2.w + a3.w);
        float* oout = out + (size_t)bh * S * D + (size_t)r0 * D;
        __builtin_nontemporal_store(o, (v4f*)(oout + (size_t)row * D + dc));
    }
}

extern "C" void kernel_launch(void* const* d_in, const int* in_sizes, int n_in,
                              void* d_out, int out_size, void* d_ws, size_t ws_size,
                              hipStream_t stream) {
    (void)in_sizes; (void)n_in; (void)out_size; (void)ws_size;
    const float* q     = (const float*)d_in[0];
    const float* k     = (const float*)d_in[1];
    const float* v     = (const float*)d_in[2];
    const float* prev  = (const float*)d_in[3];
    const float* mask  = (const float*)d_in[4];
    const float* scale = (const float*)d_in[5];

    float* out     = (float*)d_out;
    float* weights = out + (size_t)4 * 16 * 1024 * 64;
    float* scores  = weights + (size_t)4 * 16 * 1024 * 1024;

    short* kT = (short*)d_ws;                              // [BH][S][D] bf16, 8 MB
    short* vT = kT + (size_t)BH * S * D;                   // [BH][D][S] bf16, 8 MB

    transpose_bf16_kernel<<<dim3(16, BH, 2), 256, 0, stream>>>(k, v, kT, vT);
    attn_mfma_kernel<<<dim3(4096), 256, 0, stream>>>(q, kT, vT, prev, mask, scale,
                                                     out, weights, scores);
}